// Round 10
// baseline (484.119 us; speedup 1.0000x reference)
//
#include <hip/hip_runtime.h>
#include <hip/hip_bf16.h>
#include <stdint.h>

// Sizes (fixed by the problem)
#define LDIM 2048
#define BDIM 64
#define HDIM 1024
#define HCDIM 1024
// Compacted rows (mask==1 only): M_c ~ Binomial(131072, .5) ~= 65536 +- 181.
#define CAPROWS 98304   // compacted-row capacity: 180 sigma above the mean

typedef __attribute__((ext_vector_type(8))) short short8;  // 8 bf16 (4 VGPRs)
typedef __attribute__((ext_vector_type(4))) short s16x4;
typedef __attribute__((ext_vector_type(4))) float f32x4;

static __device__ __forceinline__ short f2bf(float f) {
  union { float f; uint32_t u; } a; a.f = f;
  uint32_t r = a.u + 0x7fffu + ((a.u >> 16) & 1u);  // RNE
  return (short)(r >> 16);
}
static __device__ __forceinline__ float bf2f(short s) {
  union { uint32_t u; float f; } a;
  a.u = ((uint32_t)(unsigned short)s) << 16;
  return a.f;
}
static __device__ __forceinline__ float fast_tanh(float x) {
  x = fminf(15.f, fmaxf(-15.f, x));
  float e = __expf(2.f * x);
  return (e - 1.f) * __builtin_amdgcn_rcpf(e + 1.f);
}

// direct-to-LDS 16B async copy (gfx950); dest is wave-uniform base + lane*16
#define GL16(gp, lp) __builtin_amdgcn_global_load_lds(                           \
    (const __attribute__((address_space(1))) void*)(gp),                         \
    (__attribute__((address_space(3))) void*)(lp), 16, 0, 0)

// ---------- Ks: per-chunk mask counts + exclusive scan (1 block, 512 thr) ----------
// Scan-ordered bases keep cm monotone in m -> L2-friendly m2cm reads in wsum (r6 vs r9).
__global__ void scan_mask(const int* __restrict__ mask, int* __restrict__ bases) {
  __shared__ int sc[512];
  const int t = threadIdx.x;
  int cnt = 0;
  #pragma unroll 8
  for (int b = 0; b < 64; ++b) {
    int4 v = *(const int4*)&mask[b * 2048 + t * 4];
    cnt += v.x + v.y + v.z + v.w;
  }
  sc[t] = cnt;
  __syncthreads();
  for (int off = 1; off < 512; off <<= 1) {
    int v = (t >= off) ? sc[t - off] : 0;
    __syncthreads();
    sc[t] += v;
    __syncthreads();
  }
  bases[t] = sc[t] - cnt;            // exclusive
  if (t == 511) bases[512] = sc[511];
}

// ---------- Kg: gather unmasked rows, f32 -> bf16 (512 blocks x 512 thr) ----------
__global__ void gather_rows(const float* __restrict__ prev, const int* __restrict__ mask,
                            const int* __restrict__ bases, short* __restrict__ A_c,
                            int* __restrict__ cm2m, int* __restrict__ m2cm) {
  __shared__ int smm[256];
  __shared__ int swt[4];
  const int c = blockIdx.x, t = threadIdx.x;
  const int base = bases[c];
  int bit = 0, p = 0, wv = 0;
  if (t < 256) {
    const int m = c * 256 + t;                 // l = m>>6, b = t&63
    bit = (mask[(t & 63) * 2048 + (m >> 6)] != 0);
    unsigned long long bal = __ballot(bit);
    const int lane = t & 63;
    wv = t >> 6;
    p = __popcll(bal & ((1ull << lane) - 1ull));
    if (lane == 0) swt[wv] = (int)__popcll(bal);
  }
  __syncthreads();
  if (t < 256 && bit) {
    int off = p;
    for (int i = 0; i < wv; ++i) off += swt[i];
    const int cm = base + off;
    smm[off] = t;
    if (cm < CAPROWS) {
      cm2m[cm] = c * 256 + t;
      m2cm[c * 256 + t] = cm;
    }
  }
  __syncthreads();
  const int cnt = swt[0] + swt[1] + swt[2] + swt[3];
  const int col = (t & 255) * 4;
  for (int r = (t >> 8); r < cnt; r += 2) {
    const int lm = smm[r];
    const float4 v = *(const float4*)(prev + (((size_t)(c * 256 + lm)) << 10) + col);
    if (base + r < CAPROWS) {
      s16x4 o = { f2bf(v.x), f2bf(v.y), f2bf(v.z), f2bf(v.w) };
      *(s16x4*)&A_c[(((size_t)(base + r)) << 10) + col] = o;
    }
  }
}

// ---------- K1: W_e[:, H:2H] f32 -> Wb2 bf16, FRAGMENT-MAJOR pack ----------
// Element (c, k): c16=c>>4, lr=c&15, ks=k>>5, q=(k>>3)&3, r=k&7
//   -> Wb2[(c16*32+ks)*512 + (lr*4+q)*8 + r]
// A wave's B-frag load (c16, ks) is then ONE fully-coalesced 1KB instruction
// (per-lane offset (lr*4+q)*16B is a permutation of lane*16B).
__global__ void convert_we_pack(const float* __restrict__ We, short* __restrict__ Wb2) {
  int g = blockIdx.x * 256 + threadIdx.x;
  int c = g >> 8;
  int j = (g & 255) * 4;
  float4 v = *(const float4*)(We + (size_t)c * 2048 + 1024 + j);
  s16x4 o = { f2bf(v.x), f2bf(v.y), f2bf(v.z), f2bf(v.w) };
  const int off = ((c >> 4) * 32 + (j >> 5)) * 512 + ((c & 15) * 4 + ((j >> 3) & 3)) * 8 + (j & 7);
  *(s16x4*)(Wb2 + off) = o;
}

// ---------- K0: hidbias[b][c] = W_e[c,:H]·hidden[b] + b_e[c] ----------
__global__ void hidbias_kernel(const float* __restrict__ We, const float* __restrict__ hidden,
                               const float* __restrict__ be, float* __restrict__ hidbias) {
  __shared__ float wrow[1024];
  int c0 = blockIdx.x * 16;
  int t = threadIdx.x;
  int b = t >> 2, q = t & 3;
  for (int ci = 0; ci < 16; ++ci) {
    int c = c0 + ci;
    *(float4*)&wrow[t * 4] = *(const float4*)&We[(size_t)c * 2048 + t * 4];
    __syncthreads();
    float s0 = 0.f, s1 = 0.f;
    const float* hb = hidden + b * 1024;
    #pragma unroll 8
    for (int j = 0; j < 256; j += 2) {
      int i0 = q + 4 * j;
      s0 += wrow[i0] * hb[i0];
      s1 += wrow[i0 + 4] * hb[i0 + 4];
    }
    float s = s0 + s1;
    s += __shfl_xor(s, 1);
    s += __shfl_xor(s, 2);
    if (q == 0) hidbias[b * 1024 + c] = s + be[c];
    __syncthreads();
  }
}

// ---------- K2: compacted GEMM, A-only LDS (depth-3) + B-from-L2 registers ----------
// 256x256 tile, BK=32, 8 waves (2M x 4N), wave 128x64. LDS = 4 bufs x 16 KB (A only).
// B-frags (4 x 1KB per wave per K-step) load straight from L2-resident Wb2 into
// registers, double-buffered one K-step ahead (2 named sets, unroll-by-2).
// LDS reads/K-step: 96 -> 64 (B's share removed) — LDS pipe was co-dominant.
// vmcnt ledger (queue entering iter ks: [A(ks+1)2, B(ks)4, A(ks+2)2]):
//   issue B(ks+1); VMW(6) -> lands A(ks+1)+B(ks) (A(ks) landed prior iter);
//   BAR; STAGE_A(ks+3); COMPUTE(ks).  Tail: VMW 6,6,4,0. Single barrier/K-step
//   (r6 rotation: STAGE_A(ks+3) overwrites buf (ks-1)&3, reads done pre-barrier).
__global__ __launch_bounds__(512) void energy_gemm_breg(
    const short* __restrict__ A_c, const short* __restrict__ Wb2,
    const float* __restrict__ hidbias, const float* __restrict__ Wv,
    const int* __restrict__ bases, const int* __restrict__ cm2m,
    float* __restrict__ logitsT)
{
  __shared__ short As[4][256][32];   // 64 KiB total
  __shared__ int sidx[256];
  const int Mc0 = bases[512];
  const int Mc = Mc0 < CAPROWS ? Mc0 : CAPROWS;
  const int mt = ((blockIdx.x >> 5) << 3) + (blockIdx.x & 7);
  const int nt = (blockIdx.x >> 3) & 3;
  if (mt * 256 >= Mc) return;
  const int m0 = mt * 256;
  const int n0 = nt * 256;

  const int tid = threadIdx.x;
  const int wave = tid >> 6, lane = tid & 63;
  const int q = lane >> 4, lr = lane & 15;
  const int wr = wave >> 2, wc = wave & 3;        // 2M x 4N wave grid

  // A staging: thread t -> rows r0, r0+128; 16B chunk (t&3)^((r0>>1)&3) of 64B row
  const int r0 = tid >> 2;                        // 0..127
  const int c0s = (((tid & 3) ^ ((r0 >> 1) & 3))) * 8;
  const short* asrc = A_c + (size_t)(m0 + r0) * 1024 + c0s;

#define STAGE_A(buf, ks) do {                                                  \
    const int _ko = (ks) * 32;                                                 \
    GL16(asrc + _ko,          &As[buf][0][0] + tid * 8);                       \
    GL16(asrc + 131072 + _ko, &As[buf][0][0] + tid * 8 + 4096);                \
  } while (0)

  // B-frag base: c16 = (n0 + wc*64 + ni*16)>>4 = nt*16 + wc*4 + ni
  const int c16b = nt * 16 + wc * 4;
  const int lane4 = (lr * 4 + q) * 8;             // per-lane packed offset (shorts)

#define BLOAD(dst, ks) do {                                                    \
    _Pragma("unroll")                                                          \
    for (int ni = 0; ni < 4; ++ni)                                             \
      dst[ni] = *(const short8*)(Wb2 + (size_t)((c16b + ni) * 32 + (ks)) * 512 + lane4); \
  } while (0)

  // swizzled A read chunk: q ^ ((row>>1)&3) = q ^ ((lr>>1)&3)
  const int crd = (q ^ ((lr >> 1) & 3)) * 8;

#define COMPUTE(buf, BSET) do {                                                \
    short8 af[8];                                                              \
    _Pragma("unroll")                                                          \
    for (int mi = 0; mi < 8; ++mi)                                             \
      af[mi] = *(const short8*)&As[buf][wr * 128 + mi * 16 + lr][crd];         \
    __builtin_amdgcn_s_setprio(1);                                             \
    _Pragma("unroll")                                                          \
    for (int mi = 0; mi < 8; ++mi)                                             \
      _Pragma("unroll")                                                        \
      for (int ni = 0; ni < 4; ++ni)                                           \
        acc[mi][ni] = __builtin_amdgcn_mfma_f32_16x16x32_bf16(                 \
            af[mi], BSET[ni], acc[mi][ni], 0, 0, 0);                           \
    __builtin_amdgcn_s_setprio(0);                                             \
  } while (0)

#define VMW6() asm volatile("s_waitcnt vmcnt(6)" ::: "memory")
#define VMW4() asm volatile("s_waitcnt vmcnt(4)" ::: "memory")
#define VMW0() asm volatile("s_waitcnt vmcnt(0)" ::: "memory")
#define BAR()  asm volatile("s_barrier" ::: "memory")

  f32x4 acc[8][4];
  #pragma unroll
  for (int i = 0; i < 8; ++i)
    #pragma unroll
    for (int j = 0; j < 4; ++j) acc[i][j] = (f32x4){0.f, 0.f, 0.f, 0.f};

  short8 bs0[4], bs1[4];   // B(k) lives in set k&1

  // prologue: queue = [A0, A1, B0, A2]
  STAGE_A(0, 0);
  STAGE_A(1, 1);
  BLOAD(bs0, 0);
  STAGE_A(2, 2);

  // iter macro: issue B(ks+1) into NXT; VMW6; BAR; STAGE_A(ks+3); COMPUTE(ks, CUR)
#define ITER(ks, CUR, NXT) do {                                                \
    BLOAD(NXT, (ks) + 1);                                                      \
    VMW6(); BAR();                                                             \
    STAGE_A(((ks) + 3) & 3, (ks) + 3);                                         \
    COMPUTE((ks) & 3, CUR);                                                    \
  } while (0)

  #pragma unroll 2
  for (int ks = 0; ks < 28; ks += 2) {
    ITER(ks, bs0, bs1);
    ITER(ks + 1, bs1, bs0);
  }
  // tail: ks = 28..31 (A stages end at 31; B loads end at 31)
  ITER(28, bs0, bs1);                                   // stages A31, loads B29->bs1
  { BLOAD(bs0, 30); VMW6(); BAR(); COMPUTE(1, bs1); }   // ks=29
  { BLOAD(bs1, 31); VMW4(); BAR(); COMPUTE(2, bs0); }   // ks=30
  { VMW0(); BAR(); COMPUTE(3, bs1); }                   // ks=31

#undef ITER
#undef STAGE_A
#undef BLOAD
#undef COMPUTE

  // Epilogue. D frag: col = lr (-> c), row = 4*q + reg (verified r1-r9).
  if (tid < 256) sidx[tid] = (m0 + tid < Mc) ? cm2m[m0 + tid] : -1;
  __syncthreads();

  float wv[4];
  #pragma unroll
  for (int ni = 0; ni < 4; ++ni) wv[ni] = Wv[n0 + wc * 64 + ni * 16 + lr];

  #pragma unroll
  for (int mi = 0; mi < 8; ++mi) {
    #pragma unroll
    for (int r = 0; r < 4; ++r) {
      const int row = wr * 128 + mi * 16 + 4 * q + r;   // within 256-row tile
      const int mm = sidx[row];
      if (mm >= 0) {
        const int b = mm & 63;
        float s = 0.f;
        #pragma unroll
        for (int ni = 0; ni < 4; ++ni) {
          const int c = n0 + wc * 64 + ni * 16 + lr;
          s += fast_tanh(acc[mi][ni][r] + hidbias[b * 1024 + c]) * wv[ni];
        }
        s += __shfl_xor(s, 1);
        s += __shfl_xor(s, 2);
        s += __shfl_xor(s, 4);
        s += __shfl_xor(s, 8);
        if (lr == 0) atomicAdd(&logitsT[mm], s);
      }
    }
  }
}

// ---------- K3: masked softmax (recomputed per block) + weighted sum ----------
__global__ void softmax_wsum(const short* __restrict__ A_c, const float* __restrict__ logitsT,
                             const int* __restrict__ mask, const int* __restrict__ m2cm,
                             float* __restrict__ out) {
  __shared__ float red[8];
  const int b = blockIdx.x >> 5;
  const int lc = blockIdx.x & 31;          // 32 chunks x 64 l
  const int t = threadIdx.x;

  float mx = -1e30f;
  for (int l = t; l < 2048; l += 256)
    if (mask[b * 2048 + l] != 0) mx = fmaxf(mx, logitsT[l * 64 + b]);
  #pragma unroll
  for (int o = 32; o > 0; o >>= 1) mx = fmaxf(mx, __shfl_xor(mx, o));
  if ((t & 63) == 0) red[t >> 6] = mx;
  __syncthreads();
  mx = fmaxf(fmaxf(red[0], red[1]), fmaxf(red[2], red[3]));
  float den = 0.f;
  for (int l = t; l < 2048; l += 256)
    if (mask[b * 2048 + l] != 0) den += __expf(logitsT[l * 64 + b] - mx);
  #pragma unroll
  for (int o = 32; o > 0; o >>= 1) den += __shfl_xor(den, o);
  if ((t & 63) == 0) red[4 + (t >> 6)] = den;
  __syncthreads();
  const float invd = 1.f / (red[4] + red[5] + red[6] + red[7]);

  const int h0 = t * 4;
  float4 a = {0.f, 0.f, 0.f, 0.f};
  for (int l = lc * 64; l < lc * 64 + 64; ++l) {
    if (mask[b * 2048 + l] == 0) continue;  // block-uniform branch
    const unsigned cm = (unsigned)m2cm[l * 64 + b];
    if (cm >= (unsigned)CAPROWS) continue;
    float w = __expf(logitsT[l * 64 + b] - mx) * invd;
    s16x4 v = *(const s16x4*)&A_c[((size_t)cm << 10) + h0];
    a.x += w * bf2f(v.x);
    a.y += w * bf2f(v.y);
    a.z += w * bf2f(v.z);
    a.w += w * bf2f(v.w);
  }
  atomicAdd(&out[b * 1024 + h0 + 0], a.x);
  atomicAdd(&out[b * 1024 + h0 + 1], a.y);
  atomicAdd(&out[b * 1024 + h0 + 2], a.z);
  atomicAdd(&out[b * 1024 + h0 + 3], a.w);
}

extern "C" void kernel_launch(void* const* d_in, const int* in_sizes, int n_in,
                              void* d_out, int out_size, void* d_ws, size_t ws_size,
                              hipStream_t stream) {
  const float* prev   = (const float*)d_in[0];   // [L,B,H] f32
  const float* hidden = (const float*)d_in[1];   // [B,H] f32
  const int*   mask   = (const int*)d_in[2];     // [B,L] i32
  const float* We     = (const float*)d_in[3];   // [HC,2H] f32
  const float* be     = (const float*)d_in[4];   // [HC] f32
  const float* Wv     = (const float*)d_in[5];   // [HC] f32
  float* out = (float*)d_out;                    // [1,B,H] f32

  char* ws = (char*)d_ws;
  size_t off = 0;
  short* A_c     = (short*)(ws + off); off += (size_t)CAPROWS * 1024 * 2;  // 192 MiB
  short* Wb2     = (short*)(ws + off); off += 2097152;                     // 2 MiB
  float* hidbias = (float*)(ws + off); off += 262144;
  float* logitsT = (float*)(ws + off); off += 524288;
  int*   cm2m    = (int*)  (ws + off); off += (size_t)CAPROWS * 4;
  int*   m2cm    = (int*)  (ws + off); off += 524288;
  int*   bases   = (int*)  (ws + off); off += 4096;

  hipMemsetAsync(d_out, 0, (size_t)out_size * sizeof(float), stream);
  hipMemsetAsync(logitsT, 0, 524288, stream);
  scan_mask<<<1, 512, 0, stream>>>(mask, bases);
  gather_rows<<<512, 512, 0, stream>>>(prev, mask, bases, A_c, cm2m, m2cm);
  convert_we_pack<<<1024, 256, 0, stream>>>(We, Wb2);
  hidbias_kernel<<<64, 256, 0, stream>>>(We, hidden, be, hidbias);
  energy_gemm_breg<<<2048, 512, 0, stream>>>(A_c, Wb2, hidbias, Wv, bases, cm2m, logitsT);
  softmax_wsum<<<2048, 256, 0, stream>>>(A_c, logitsT, mask, m2cm, out);
}